// Round 8
// baseline (109.342 us; speedup 1.0000x reference)
//
#include <hip/hip_runtime.h>
#include <hip/hip_bf16.h>
#include <cstdint>
#include <cstddef>

typedef __bf16 bf16_t;
typedef bf16_t bf16x8 __attribute__((ext_vector_type(8)));
typedef bf16_t bf16x4 __attribute__((ext_vector_type(4)));
typedef float  f32x4  __attribute__((ext_vector_type(4)));
typedef unsigned int u32;

#define BROWS 4096
#define NV    8192
#define KD    1024
#define NT    16    // GEMM K-tiles (1024 / 64)
#define ST    48    // marginal buckets (6 concepts x 8)
#define LOG2E 1.44269504088896340736f

// async global->LDS, 16B per lane; LDS dst is wave-uniform base + lane*16
#define GLL(gsrc, ldst) \
  __builtin_amdgcn_global_load_lds((const __attribute__((address_space(1))) u32*)(gsrc), \
                                   (__attribute__((address_space(3))) u32*)(ldst), 16, 0, 0)
#define FENCE asm volatile("" ::: "memory")

// ---------------- f32 -> bf16 conversion ----------------
__global__ void cvt_kernel(const float* __restrict__ src, bf16_t* __restrict__ dst, int n4) {
  int idx = blockIdx.x * blockDim.x + threadIdx.x;
  int stride = gridDim.x * blockDim.x;
  for (int i = idx; i < n4; i += stride) {
    float4 v = ((const float4*)src)[i];
    bf16x4 o;
    o[0] = (bf16_t)v.x; o[1] = (bf16_t)v.y; o[2] = (bf16_t)v.z; o[3] = (bf16_t)v.w;
    ((bf16x4*)dst)[i] = o;
  }
}

// ---------------- build S2^T: one-hot indicator, bf16 [48][NV], swizzle-baked ----
__global__ void build_s2t_kernel(const int* __restrict__ vstate, bf16_t* __restrict__ s2t) {
  int g = blockIdx.x * blockDim.x + threadIdx.x;   // g = b*NV + ig
  if (g >= ST * NV) return;
  int b = g >> 13;
  int ig = g & (NV - 1);
  int c = b >> 3;
  int d = b & 7;
  int src = ig ^ ((b & 7) << 3);
  int dig = (vstate[src] >> (15 - 3 * c)) & 7;
  s2t[g] = (bf16_t)(dig == d ? 1.0f : 0.0f);
}

// ---------------- fused GEMM + exp + marginal ----------------
// D[i=state][j=batch] = sum_k W[i][k]*E[j][k]; 256x256 tile, BK=64, 8 waves.
// m201-faithful 4-phase/K-tile schedule over an 8-slot circular half-tile LDS:
// slots 16KB: {A-kh0, B-kh0, A-kh1, B-kh1} x (kt parity). Per phase:
// {4-8 ds_read_b128, stage 1 half-tile (2 GLL), s_barrier, lgkmcnt(0)+
//  sched_barrier, setprio(1), 16 MFMA, setprio(0), [vmcnt(4) at q1/q3], s_barrier}.
// Ledger-verified: every vmcnt(4) drains exactly the 2 half-tiles consumed after
// the following barrier (2-4-phase flight, never vmcnt(0) in-loop); a slot's data
// is always guaranteed by a barrier BEFORE the phase that ds_reads it; slot
// overwrites trail last-read by >=3 barriers.
// Swizzle (T2, 64B rows): phys = logical ^ ((row&6)<<3); staging source
// pre-permuted kslot = (l&3)^((l>>3)&3) (both-sides involution, rule #21).
__global__ __launch_bounds__(512, 2)
void gemm_fused_kernel(const bf16_t* __restrict__ W, const bf16_t* __restrict__ E,
                       const float* __restrict__ bias, const bf16_t* __restrict__ s2t,
                       float* __restrict__ part) {
  __shared__ __align__(16) char lds[131072];   // 8 x 16KB slots

  const int t    = threadIdx.x;
  const int lane = t & 63;
  const int wv   = t >> 6;      // 0..7
  const int wm   = wv >> 2;     // 0..1  (state half)
  const int wn   = wv & 3;      // 0..3  (batch quarter)
  const int fr   = lane & 15;
  const int fq   = lane >> 4;

  // XCD swizzle: 512 blocks % 8 == 0 -> simple form bijective
  int bid = blockIdx.x;
  int wg  = (bid & 7) * 64 + (bid >> 3);
  const int stile = wg >> 4;    // 0..31 (state tile)
  const int btile = wg & 15;    // 0..15 (batch tile)
  const int st0 = stile * 256;
  const int bt0 = btile * 256;

  // ---- staging geometry: half-tile = 256 rows x 32 k = 16KB = 16 chunks.
  // Wave wv stages chunks {2wv, 2wv+1} (rows wv*32 .. +31). Lane l: row-in-chunk
  // = l>>2, phys k-slot = l&3; source fetches logical k-slot (l&3)^((l>>3)&3).
  const int srow = lane >> 2;
  const int skel = ((lane & 3) ^ ((lane >> 3) & 3)) * 8;
  const bf16_t* aptr = W + (size_t)(st0 + wv * 32 + srow) * KD + skel;
  const bf16_t* bptr = E + (size_t)(bt0 + wv * 32 + srow) * KD + skel;
  const int dchunk = (wv * 2) * 1024;

  // ---- ds_read geometry: row stride 64B; phys = logical ^ ((row&6)<<3) ----
  const int xsw    = (fr & 6) << 3;
  const int a_base = wm * 8192 + ((fr * 64 + fq * 16) ^ xsw);
  const int b_base = wn * 4096 + ((fr * 64 + fq * 16) ^ xsw);

  f32x4 acc[8][4] = {};

  // ---- prologue: stage kt0's 4 halves, FIFO order Ak0,Bk0,Ak1,Bk1 ----
  GLL(aptr,                &lds[0 * 16384 + dchunk]);
  GLL(aptr + 16 * KD,      &lds[0 * 16384 + dchunk + 1024]);
  GLL(bptr,                &lds[1 * 16384 + dchunk]);
  GLL(bptr + 16 * KD,      &lds[1 * 16384 + dchunk + 1024]);
  GLL(aptr + 32,           &lds[2 * 16384 + dchunk]);
  GLL(aptr + 32 + 16 * KD, &lds[2 * 16384 + dchunk + 1024]);
  GLL(bptr + 32,           &lds[3 * 16384 + dchunk]);
  GLL(bptr + 32 + 16 * KD, &lds[3 * 16384 + dchunk + 1024]);
  asm volatile("s_waitcnt vmcnt(4)" ::: "memory");   // Ak0,Bk0 resident
  __builtin_amdgcn_s_barrier();
  FENCE;

  for (int kt = 0; kt < NT; ++kt) {
    const int cb = (kt & 1) * 4;
    const int nb = ((kt + 1) & 1) * 4;
    const char* sA0 = &lds[(cb + 0) * 16384];
    const char* sB0 = &lds[(cb + 1) * 16384];
    const char* sA1 = &lds[(cb + 2) * 16384];
    const char* sB1 = &lds[(cb + 3) * 16384];
    const bool pf = (kt + 1 < NT);
    const int ko = (kt + 1) * 64;   // next-tile k element offset

    bf16x8 a[4], b0[4], b1[4];

    // ===== q=0: read Bk0(4) + Ak0 m0-3(4); stage Ak0(kt+1) =====
#pragma unroll
    for (int n = 0; n < 4; ++n)
      b0[n] = *(const bf16x8*)(sB0 + b_base + n * 1024);
#pragma unroll
    for (int mi = 0; mi < 4; ++mi)
      a[mi] = *(const bf16x8*)(sA0 + a_base + mi * 1024);
    if (pf) {
      GLL(aptr + ko,           &lds[(nb + 0) * 16384 + dchunk]);
      GLL(aptr + ko + 16 * KD, &lds[(nb + 0) * 16384 + dchunk + 1024]);
    }
    FENCE; __builtin_amdgcn_s_barrier();
    asm volatile("s_waitcnt lgkmcnt(0)" ::: "memory");
    __builtin_amdgcn_sched_barrier(0);
    __builtin_amdgcn_s_setprio(1);
#pragma unroll
    for (int mi = 0; mi < 4; ++mi)
#pragma unroll
      for (int n = 0; n < 4; ++n)
        acc[mi][n] = __builtin_amdgcn_mfma_f32_16x16x32_bf16(a[mi], b0[n], acc[mi][n], 0, 0, 0);
    __builtin_amdgcn_s_setprio(0);
    FENCE; __builtin_amdgcn_s_barrier(); FENCE;

    // ===== q=1: read Ak0 m4-7(4); stage Bk0(kt+1); gate kh1 =====
#pragma unroll
    for (int mi = 0; mi < 4; ++mi)
      a[mi] = *(const bf16x8*)(sA0 + a_base + (4 + mi) * 1024);
    if (pf) {
      GLL(bptr + ko,           &lds[(nb + 1) * 16384 + dchunk]);
      GLL(bptr + ko + 16 * KD, &lds[(nb + 1) * 16384 + dchunk + 1024]);
    }
    FENCE; __builtin_amdgcn_s_barrier();
    asm volatile("s_waitcnt lgkmcnt(0)" ::: "memory");
    __builtin_amdgcn_sched_barrier(0);
    __builtin_amdgcn_s_setprio(1);
#pragma unroll
    for (int mi = 0; mi < 4; ++mi)
#pragma unroll
      for (int n = 0; n < 4; ++n)
        acc[4 + mi][n] = __builtin_amdgcn_mfma_f32_16x16x32_bf16(a[mi], b0[n], acc[4 + mi][n], 0, 0, 0);
    __builtin_amdgcn_s_setprio(0);
    // drain Ak1(kt),Bk1(kt) (2-4 phase flight); bar2 = guarantee point for q2 reads
    if (pf) asm volatile("s_waitcnt vmcnt(4)" ::: "memory");
    else    asm volatile("s_waitcnt vmcnt(0)" ::: "memory");
    FENCE; __builtin_amdgcn_s_barrier(); FENCE;

    // ===== q=2: read Bk1(4) + Ak1 m0-3(4); stage Ak1(kt+1) =====
#pragma unroll
    for (int n = 0; n < 4; ++n)
      b1[n] = *(const bf16x8*)(sB1 + b_base + n * 1024);
#pragma unroll
    for (int mi = 0; mi < 4; ++mi)
      a[mi] = *(const bf16x8*)(sA1 + a_base + mi * 1024);
    if (pf) {
      GLL(aptr + ko + 32,           &lds[(nb + 2) * 16384 + dchunk]);
      GLL(aptr + ko + 32 + 16 * KD, &lds[(nb + 2) * 16384 + dchunk + 1024]);
    }
    FENCE; __builtin_amdgcn_s_barrier();
    asm volatile("s_waitcnt lgkmcnt(0)" ::: "memory");
    __builtin_amdgcn_sched_barrier(0);
    __builtin_amdgcn_s_setprio(1);
#pragma unroll
    for (int mi = 0; mi < 4; ++mi)
#pragma unroll
      for (int n = 0; n < 4; ++n)
        acc[mi][n] = __builtin_amdgcn_mfma_f32_16x16x32_bf16(a[mi], b1[n], acc[mi][n], 0, 0, 0);
    __builtin_amdgcn_s_setprio(0);
    FENCE; __builtin_amdgcn_s_barrier(); FENCE;

    // ===== q=3: read Ak1 m4-7(4); stage Bk1(kt+1); gate next kh0 =====
#pragma unroll
    for (int mi = 0; mi < 4; ++mi)
      a[mi] = *(const bf16x8*)(sA1 + a_base + (4 + mi) * 1024);
    if (pf) {
      GLL(bptr + ko + 32,           &lds[(nb + 3) * 16384 + dchunk]);
      GLL(bptr + ko + 32 + 16 * KD, &lds[(nb + 3) * 16384 + dchunk + 1024]);
    }
    FENCE; __builtin_amdgcn_s_barrier();
    asm volatile("s_waitcnt lgkmcnt(0)" ::: "memory");
    __builtin_amdgcn_sched_barrier(0);
    __builtin_amdgcn_s_setprio(1);
#pragma unroll
    for (int mi = 0; mi < 4; ++mi)
#pragma unroll
      for (int n = 0; n < 4; ++n)
        acc[4 + mi][n] = __builtin_amdgcn_mfma_f32_16x16x32_bf16(a[mi], b1[n], acc[4 + mi][n], 0, 0, 0);
    __builtin_amdgcn_s_setprio(0);
    // drain Ak0(kt+1),Bk0(kt+1) (2-3 phase flight); bar2 guarantees next q0 reads
    if (pf) asm volatile("s_waitcnt vmcnt(4)" ::: "memory");
    FENCE; __builtin_amdgcn_s_barrier(); FENCE;
  }

  // ================= fused epilogue (unchanged from R6) =================
  char* const ldsf = &lds[0];
  {
#pragma unroll
    for (int q = 0; q < 3; ++q) {
      const bf16_t* src = s2t + (size_t)(wv * 6 + q * 2 + (lane >> 5)) * NV
                          + st0 + (lane & 31) * 8;
      GLL(src, ldsf + 98304 + wv * 3072 + q * 1024);
    }
  }

  float* const ppart = part + ((size_t)stile * BROWS + bt0) * ST;

#pragma unroll
  for (int pass = 0; pass < 2; ++pass) {
    if ((wn >> 1) == pass) {
#pragma unroll
      for (int m = 0; m < 8; ++m) {
        const float4 bb = *(const float4*)&bias[st0 + wm * 128 + m * 16 + fq * 4];
#pragma unroll
        for (int n = 0; n < 4; ++n) {
          bf16x4 ev;
          ev[0] = (bf16_t)exp2f((acc[m][n][0] + bb.x) * LOG2E);
          ev[1] = (bf16_t)exp2f((acc[m][n][1] + bb.y) * LOG2E);
          ev[2] = (bf16_t)exp2f((acc[m][n][2] + bb.z) * LOG2E);
          ev[3] = (bf16_t)exp2f((acc[m][n][3] + bb.w) * LOG2E);
          const int jh = (wn & 1) * 64 + n * 16 + fr;          // half-local batch row
          const int ib = (wm * 128 + m * 16 + fq * 4) * 2;     // state byte offset
          *(bf16x4*)(ldsf + jh * 512 + (ib ^ ((fr & 7) << 4))) = ev;
        }
      }
    }
    if (pass == 0) asm volatile("s_waitcnt vmcnt(0)" ::: "memory");  // S2T resident
    __syncthreads();

    f32x4 acc2[3] = {{0.f,0.f,0.f,0.f},{0.f,0.f,0.f,0.f},{0.f,0.f,0.f,0.f}};
#pragma unroll
    for (int k2 = 0; k2 < 8; ++k2) {
      const int ko2 = (k2 * 64 + fq * 16) ^ ((fr & 7) << 4);
      const bf16x8 ea = *(const bf16x8*)(ldsf + (wv * 16 + fr) * 512 + ko2);
#pragma unroll
      for (int n2 = 0; n2 < 3; ++n2) {
        const bf16x8 sb = *(const bf16x8*)(ldsf + 98304 + (n2 * 16 + fr) * 512 + ko2);
        acc2[n2] = __builtin_amdgcn_mfma_f32_16x16x32_bf16(ea, sb, acc2[n2], 0, 0, 0);
      }
    }
    const int jg = pass * 128 + wv * 16 + fq * 4;
#pragma unroll
    for (int n2 = 0; n2 < 3; ++n2)
#pragma unroll
      for (int r = 0; r < 4; ++r)
        ppart[(size_t)(jg + r) * ST + n2 * 16 + fr] = acc2[n2][r];
    __syncthreads();
  }
}

// ---------------- reduce partials over 32 state-tiles + normalize ----------------
__global__ __launch_bounds__(64)
void reduce_kernel(const float* __restrict__ part, float* __restrict__ out) {
  const int b = blockIdx.x;
  const int t = threadIdx.x;
  __shared__ float fin[ST];
  if (t < ST) {
    float s = 0.f;
#pragma unroll
    for (int mt = 0; mt < 32; ++mt)
      s += part[((size_t)mt * BROWS + b) * ST + t];
    fin[t] = s;
  }
  __syncthreads();
  if (t < ST) {
    float total = fin[0] + fin[1] + fin[2] + fin[3] + fin[4] + fin[5] + fin[6] + fin[7];
    out[(size_t)(t >> 3) * BROWS * 8 + (size_t)b * 8 + (t & 7)] = fin[t] / total;
  }
}

// ---------------- launch ----------------
extern "C" void kernel_launch(void* const* d_in, const int* in_sizes, int n_in,
                              void* d_out, int out_size, void* d_ws, size_t ws_size,
                              hipStream_t stream) {
  const float* E    = (const float*)d_in[0];
  const float* W    = (const float*)d_in[1];
  const float* bias = (const float*)d_in[2];
  const int*   vs   = (const int*)d_in[3];
  float* out = (float*)d_out;

  char* ws = (char*)d_ws;
  size_t off = 0;
  bf16_t* Eb   = (bf16_t*)(ws + off); off += (size_t)BROWS * KD * 2;           // 8 MB
  bf16_t* Wb   = (bf16_t*)(ws + off); off += (size_t)NV * KD * 2;              // 16 MB
  bf16_t* s2t  = (bf16_t*)(ws + off); off += (size_t)ST * NV * 2;              // 786 KB
  float*  part = (float*)(ws + off);  off += (size_t)32 * BROWS * ST * 4;      // 25 MB

  build_s2t_kernel<<<(ST * NV + 255) / 256, 256, 0, stream>>>(vs, s2t);
  cvt_kernel<<<2048, 256, 0, stream>>>(E, Eb, BROWS * KD / 4);
  cvt_kernel<<<2048, 256, 0, stream>>>(W, Wb, NV * KD / 4);
  gemm_fused_kernel<<<512, 512, 0, stream>>>(Wb, Eb, bias, s2t, part);
  reduce_kernel<<<BROWS, 64, 0, stream>>>(part, out);
}

// Round 9
// 107.986 us; speedup vs baseline: 1.0126x; 1.0126x over previous
//
#include <hip/hip_runtime.h>
#include <hip/hip_bf16.h>
#include <cstdint>
#include <cstddef>

typedef __bf16 bf16_t;
typedef bf16_t bf16x8 __attribute__((ext_vector_type(8)));
typedef bf16_t bf16x4 __attribute__((ext_vector_type(4)));
typedef float  f32x4  __attribute__((ext_vector_type(4)));
typedef unsigned int u32;

#define BROWS 4096
#define NV    8192
#define KD    1024
#define NT    16    // GEMM K-tiles (1024 / 64)
#define ST    48    // marginal buckets (6 concepts x 8)
#define LOG2E 1.44269504088896340736f

// async global->LDS, 16B per lane; LDS dst is wave-uniform base + lane*16
#define GLL(gsrc, ldst) \
  __builtin_amdgcn_global_load_lds((const __attribute__((address_space(1))) u32*)(gsrc), \
                                   (__attribute__((address_space(3))) u32*)(ldst), 16, 0, 0)
#define FENCE asm volatile("" ::: "memory")

// ---------------- f32 -> bf16 conversion (E and W in one launch) ----------------
__global__ void cvt2_kernel(const float* __restrict__ E, const float* __restrict__ W,
                            bf16_t* __restrict__ Eb, bf16_t* __restrict__ Wb) {
  const int nE = BROWS * KD / 4;       // float4 count for E
  const int nT = nE + NV * KD / 4;     // total float4 count
  int idx = blockIdx.x * blockDim.x + threadIdx.x;
  int stride = gridDim.x * blockDim.x;
  for (int i = idx; i < nT; i += stride) {
    const float4* s; bf16x4* d; int j;
    if (i < nE) { s = (const float4*)E; d = (bf16x4*)Eb; j = i; }
    else        { s = (const float4*)W; d = (bf16x4*)Wb; j = i - nE; }
    float4 v = s[j];
    bf16x4 o;
    o[0] = (bf16_t)v.x; o[1] = (bf16_t)v.y; o[2] = (bf16_t)v.z; o[3] = (bf16_t)v.w;
    d[j] = o;
  }
}

// ---------------- build S2^T: one-hot indicator, bf16 [48][NV], swizzle-baked ----
__global__ void build_s2t_kernel(const int* __restrict__ vstate, bf16_t* __restrict__ s2t) {
  int g = blockIdx.x * blockDim.x + threadIdx.x;   // g = b*NV + ig
  if (g >= ST * NV) return;
  int b = g >> 13;
  int ig = g & (NV - 1);
  int c = b >> 3;
  int d = b & 7;
  int src = ig ^ ((b & 7) << 3);
  int dig = (vstate[src] >> (15 - 3 * c)) & 7;
  s2t[g] = (bf16_t)(dig == d ? 1.0f : 0.0f);
}

// ---------------- fused GEMM + exp + marginal ----------------
// D[i=state][j=batch] = sum_k W[i][k]*E[j][k]; 256x256 tile, BK=64, 8 waves.
// 4-phase/K-tile schedule over 8-slot circular half-tile LDS (R7 structure)
// with DEEP prefetch (this round's change): half-tile PAIRS staged 3 phases
// before their gate:
//   q0 stages {Ak0,Bk0}(kt+1) [4 GLL]; q2 stages {Ak1,Bk1}(kt+1) [4 GLL];
//   gate end-q1: vmcnt(4) drains {Ak1,Bk1}(kt)   [staged q2(kt-1), 3-phase flight]
//   gate end-q3: vmcnt(4) drains {Ak0,Bk0}(kt+1) [staged q0(kt),   3-phase flight]
// Max 8 loads outstanding; never vmcnt(0) in-loop. Ledger + slot-overwrite
// safety verified (stage-issue always >=1 barrier after slot's last read).
// Swizzle (T2, 64B rows): phys = logical ^ ((row&6)<<3); staging source
// pre-permuted kslot = (l&3)^((l>>3)&3) (both-sides involution, rule #21).
__global__ __launch_bounds__(512, 2)
void gemm_fused_kernel(const bf16_t* __restrict__ W, const bf16_t* __restrict__ E,
                       const float* __restrict__ bias, const bf16_t* __restrict__ s2t,
                       float* __restrict__ part) {
  __shared__ __align__(16) char lds[131072];   // 8 x 16KB slots

  const int t    = threadIdx.x;
  const int lane = t & 63;
  const int wv   = t >> 6;      // 0..7
  const int wm   = wv >> 2;     // 0..1  (state half)
  const int wn   = wv & 3;      // 0..3  (batch quarter)
  const int fr   = lane & 15;
  const int fq   = lane >> 4;

  // XCD swizzle: 512 blocks % 8 == 0 -> simple form bijective
  int bid = blockIdx.x;
  int wg  = (bid & 7) * 64 + (bid >> 3);
  const int stile = wg >> 4;    // 0..31 (state tile)
  const int btile = wg & 15;    // 0..15 (batch tile)
  const int st0 = stile * 256;
  const int bt0 = btile * 256;

  // ---- staging geometry: half-tile = 256 rows x 32 k = 16KB = 16 chunks.
  // Wave wv stages chunks {2wv, 2wv+1}. Lane l: row-in-chunk = l>>2,
  // phys k-slot = l&3; source fetches logical k-slot (l&3)^((l>>3)&3).
  const int srow = lane >> 2;
  const int skel = ((lane & 3) ^ ((lane >> 3) & 3)) * 8;
  const bf16_t* aptr = W + (size_t)(st0 + wv * 32 + srow) * KD + skel;
  const bf16_t* bptr = E + (size_t)(bt0 + wv * 32 + srow) * KD + skel;
  const int dchunk = (wv * 2) * 1024;

  // ---- ds_read geometry: row stride 64B; phys = logical ^ ((row&6)<<3) ----
  const int xsw    = (fr & 6) << 3;
  const int a_base = wm * 8192 + ((fr * 64 + fq * 16) ^ xsw);
  const int b_base = wn * 4096 + ((fr * 64 + fq * 16) ^ xsw);

  f32x4 acc[8][4] = {};

  // ---- prologue: stage kt0's 4 halves, FIFO order Ak0,Bk0,Ak1,Bk1 ----
  GLL(aptr,                &lds[0 * 16384 + dchunk]);
  GLL(aptr + 16 * KD,      &lds[0 * 16384 + dchunk + 1024]);
  GLL(bptr,                &lds[1 * 16384 + dchunk]);
  GLL(bptr + 16 * KD,      &lds[1 * 16384 + dchunk + 1024]);
  GLL(aptr + 32,           &lds[2 * 16384 + dchunk]);
  GLL(aptr + 32 + 16 * KD, &lds[2 * 16384 + dchunk + 1024]);
  GLL(bptr + 32,           &lds[3 * 16384 + dchunk]);
  GLL(bptr + 32 + 16 * KD, &lds[3 * 16384 + dchunk + 1024]);
  asm volatile("s_waitcnt vmcnt(4)" ::: "memory");   // Ak0,Bk0 resident
  __builtin_amdgcn_s_barrier();
  FENCE;

#pragma unroll 2
  for (int kt = 0; kt < NT; ++kt) {
    const int cb = (kt & 1) * 4;
    const int nb = ((kt + 1) & 1) * 4;
    const char* sA0 = &lds[(cb + 0) * 16384];
    const char* sB0 = &lds[(cb + 1) * 16384];
    const char* sA1 = &lds[(cb + 2) * 16384];
    const char* sB1 = &lds[(cb + 3) * 16384];
    const bool pf = (kt + 1 < NT);
    const int ko = (kt + 1) * 64;   // next-tile k element offset

    bf16x8 a[4], b0[4], b1[4];

    // ===== q=0: read Bk0(4) + Ak0 m0-3(4); stage PAIR0(kt+1) = Ak0,Bk0 =====
#pragma unroll
    for (int n = 0; n < 4; ++n)
      b0[n] = *(const bf16x8*)(sB0 + b_base + n * 1024);
#pragma unroll
    for (int mi = 0; mi < 4; ++mi)
      a[mi] = *(const bf16x8*)(sA0 + a_base + mi * 1024);
    if (pf) {
      GLL(aptr + ko,           &lds[(nb + 0) * 16384 + dchunk]);
      GLL(aptr + ko + 16 * KD, &lds[(nb + 0) * 16384 + dchunk + 1024]);
      GLL(bptr + ko,           &lds[(nb + 1) * 16384 + dchunk]);
      GLL(bptr + ko + 16 * KD, &lds[(nb + 1) * 16384 + dchunk + 1024]);
    }
    FENCE; __builtin_amdgcn_s_barrier();
    asm volatile("s_waitcnt lgkmcnt(0)" ::: "memory");
    __builtin_amdgcn_sched_barrier(0);
    __builtin_amdgcn_s_setprio(1);
#pragma unroll
    for (int mi = 0; mi < 4; ++mi)
#pragma unroll
      for (int n = 0; n < 4; ++n)
        acc[mi][n] = __builtin_amdgcn_mfma_f32_16x16x32_bf16(a[mi], b0[n], acc[mi][n], 0, 0, 0);
    __builtin_amdgcn_s_setprio(0);
    FENCE; __builtin_amdgcn_s_barrier(); FENCE;

    // ===== q=1: read Ak0 m4-7(4); gate PAIR1(kt) [3-phase flight] =====
#pragma unroll
    for (int mi = 0; mi < 4; ++mi)
      a[mi] = *(const bf16x8*)(sA0 + a_base + (4 + mi) * 1024);
    FENCE; __builtin_amdgcn_s_barrier();
    asm volatile("s_waitcnt lgkmcnt(0)" ::: "memory");
    __builtin_amdgcn_sched_barrier(0);
    __builtin_amdgcn_s_setprio(1);
#pragma unroll
    for (int mi = 0; mi < 4; ++mi)
#pragma unroll
      for (int n = 0; n < 4; ++n)
        acc[4 + mi][n] = __builtin_amdgcn_mfma_f32_16x16x32_bf16(a[mi], b0[n], acc[4 + mi][n], 0, 0, 0);
    __builtin_amdgcn_s_setprio(0);
    if (pf) asm volatile("s_waitcnt vmcnt(4)" ::: "memory");
    else    asm volatile("s_waitcnt vmcnt(0)" ::: "memory");
    FENCE; __builtin_amdgcn_s_barrier(); FENCE;

    // ===== q=2: read Bk1(4) + Ak1 m0-3(4); stage PAIR1(kt+1) = Ak1,Bk1 =====
#pragma unroll
    for (int n = 0; n < 4; ++n)
      b1[n] = *(const bf16x8*)(sB1 + b_base + n * 1024);
#pragma unroll
    for (int mi = 0; mi < 4; ++mi)
      a[mi] = *(const bf16x8*)(sA1 + a_base + mi * 1024);
    if (pf) {
      GLL(aptr + ko + 32,           &lds[(nb + 2) * 16384 + dchunk]);
      GLL(aptr + ko + 32 + 16 * KD, &lds[(nb + 2) * 16384 + dchunk + 1024]);
      GLL(bptr + ko + 32,           &lds[(nb + 3) * 16384 + dchunk]);
      GLL(bptr + ko + 32 + 16 * KD, &lds[(nb + 3) * 16384 + dchunk + 1024]);
    }
    FENCE; __builtin_amdgcn_s_barrier();
    asm volatile("s_waitcnt lgkmcnt(0)" ::: "memory");
    __builtin_amdgcn_sched_barrier(0);
    __builtin_amdgcn_s_setprio(1);
#pragma unroll
    for (int mi = 0; mi < 4; ++mi)
#pragma unroll
      for (int n = 0; n < 4; ++n)
        acc[mi][n] = __builtin_amdgcn_mfma_f32_16x16x32_bf16(a[mi], b1[n], acc[mi][n], 0, 0, 0);
    __builtin_amdgcn_s_setprio(0);
    FENCE; __builtin_amdgcn_s_barrier(); FENCE;

    // ===== q=3: read Ak1 m4-7(4); gate PAIR0(kt+1) [3-phase flight] =====
#pragma unroll
    for (int mi = 0; mi < 4; ++mi)
      a[mi] = *(const bf16x8*)(sA1 + a_base + (4 + mi) * 1024);
    FENCE; __builtin_amdgcn_s_barrier();
    asm volatile("s_waitcnt lgkmcnt(0)" ::: "memory");
    __builtin_amdgcn_sched_barrier(0);
    __builtin_amdgcn_s_setprio(1);
#pragma unroll
    for (int mi = 0; mi < 4; ++mi)
#pragma unroll
      for (int n = 0; n < 4; ++n)
        acc[4 + mi][n] = __builtin_amdgcn_mfma_f32_16x16x32_bf16(a[mi], b1[n], acc[4 + mi][n], 0, 0, 0);
    __builtin_amdgcn_s_setprio(0);
    if (pf) asm volatile("s_waitcnt vmcnt(4)" ::: "memory");
    FENCE; __builtin_amdgcn_s_barrier(); FENCE;
  }

  // ================= fused epilogue =================
  char* const ldsf = &lds[0];
  {
#pragma unroll
    for (int q = 0; q < 3; ++q) {
      const bf16_t* src = s2t + (size_t)(wv * 6 + q * 2 + (lane >> 5)) * NV
                          + st0 + (lane & 31) * 8;
      GLL(src, ldsf + 98304 + wv * 3072 + q * 1024);
    }
  }

  // part layout: [batch][stile][ST]  (contiguous 1536 floats per batch row)
  float* const ppart = part + (size_t)bt0 * (32 * ST) + (size_t)stile * ST;

#pragma unroll
  for (int pass = 0; pass < 2; ++pass) {
    if ((wn >> 1) == pass) {
#pragma unroll
      for (int m = 0; m < 8; ++m) {
        const float4 bb = *(const float4*)&bias[st0 + wm * 128 + m * 16 + fq * 4];
#pragma unroll
        for (int n = 0; n < 4; ++n) {
          bf16x4 ev;
          ev[0] = (bf16_t)exp2f((acc[m][n][0] + bb.x) * LOG2E);
          ev[1] = (bf16_t)exp2f((acc[m][n][1] + bb.y) * LOG2E);
          ev[2] = (bf16_t)exp2f((acc[m][n][2] + bb.z) * LOG2E);
          ev[3] = (bf16_t)exp2f((acc[m][n][3] + bb.w) * LOG2E);
          const int jh = (wn & 1) * 64 + n * 16 + fr;          // half-local batch row
          const int ib = (wm * 128 + m * 16 + fq * 4) * 2;     // state byte offset
          *(bf16x4*)(ldsf + jh * 512 + (ib ^ ((fr & 7) << 4))) = ev;
        }
      }
    }
    if (pass == 0) asm volatile("s_waitcnt vmcnt(0)" ::: "memory");  // S2T resident
    __syncthreads();

    f32x4 acc2[3] = {{0.f,0.f,0.f,0.f},{0.f,0.f,0.f,0.f},{0.f,0.f,0.f,0.f}};
#pragma unroll
    for (int k2 = 0; k2 < 8; ++k2) {
      const int ko2 = (k2 * 64 + fq * 16) ^ ((fr & 7) << 4);
      const bf16x8 ea = *(const bf16x8*)(ldsf + (wv * 16 + fr) * 512 + ko2);
#pragma unroll
      for (int n2 = 0; n2 < 3; ++n2) {
        const bf16x8 sb = *(const bf16x8*)(ldsf + 98304 + (n2 * 16 + fr) * 512 + ko2);
        acc2[n2] = __builtin_amdgcn_mfma_f32_16x16x32_bf16(ea, sb, acc2[n2], 0, 0, 0);
      }
    }
    const int jg = pass * 128 + wv * 16 + fq * 4;
#pragma unroll
    for (int n2 = 0; n2 < 3; ++n2)
#pragma unroll
      for (int r = 0; r < 4; ++r)
        ppart[(size_t)(jg + r) * (32 * ST) + n2 * 16 + fr] = acc2[n2][r];
    __syncthreads();
  }
}

// ---------------- reduce partials over 32 state-tiles + normalize ----------------
// part[batch][stile][ST]: each block reads a contiguous 6 KB row.
__global__ __launch_bounds__(64)
void reduce_kernel(const float* __restrict__ part, float* __restrict__ out) {
  const int b = blockIdx.x;
  const int t = threadIdx.x;
  __shared__ float fin[ST];
  if (t < ST) {
    const float* p = part + (size_t)b * (32 * ST) + t;
    float s = 0.f;
#pragma unroll
    for (int mt = 0; mt < 32; ++mt)
      s += p[mt * ST];
    fin[t] = s;
  }
  __syncthreads();
  if (t < ST) {
    float total = fin[0] + fin[1] + fin[2] + fin[3] + fin[4] + fin[5] + fin[6] + fin[7];
    out[(size_t)(t >> 3) * BROWS * 8 + (size_t)b * 8 + (t & 7)] = fin[t] / total;
  }
}

// ---------------- launch ----------------
extern "C" void kernel_launch(void* const* d_in, const int* in_sizes, int n_in,
                              void* d_out, int out_size, void* d_ws, size_t ws_size,
                              hipStream_t stream) {
  const float* E    = (const float*)d_in[0];
  const float* W    = (const float*)d_in[1];
  const float* bias = (const float*)d_in[2];
  const int*   vs   = (const int*)d_in[3];
  float* out = (float*)d_out;

  char* ws = (char*)d_ws;
  size_t off = 0;
  bf16_t* Eb   = (bf16_t*)(ws + off); off += (size_t)BROWS * KD * 2;           // 8 MB
  bf16_t* Wb   = (bf16_t*)(ws + off); off += (size_t)NV * KD * 2;              // 16 MB
  bf16_t* s2t  = (bf16_t*)(ws + off); off += (size_t)ST * NV * 2;              // 786 KB
  float*  part = (float*)(ws + off);  off += (size_t)BROWS * 32 * ST * 4;      // 25 MB

  build_s2t_kernel<<<(ST * NV + 255) / 256, 256, 0, stream>>>(vs, s2t);
  cvt2_kernel<<<3072, 256, 0, stream>>>(E, W, Eb, Wb);
  gemm_fused_kernel<<<512, 512, 0, stream>>>(Wb, Eb, bias, s2t, part);
  reduce_kernel<<<BROWS, 64, 0, stream>>>(part, out);
}